// Round 12
// baseline (247585.229 us; speedup 1.0000x reference)
//
#include <hip/hip_runtime.h>
#include <stdint.h>

// ---------------------------------------------------------------------------
// GRU encoder (B=128,T=512,D=512,H=512,L=256), MI355X gfx950.
//
// R16: XCD-LOCAL RING, hardware-verified, with deadlock-proof mirror.
// 512 blocks launched; each reads HW_REG_XCC_ID; blocks on XCD 0 claim ring
// roles 0..63 via atomic ticket (pigeonhole: 2 blocks/CU x 32 CUs/XCD).
// Ring protocol = R4/R14 (store->drain->flag->poll->load), but at sc0:
// intra-XCD stores write through to the shared XCD-0 L2 and sc0 loads bypass
// L1 and read that L2 -> ~300cy RTs instead of ~2000cy (R4..R14 measured the
// cross-XCD ring floor at 9400cy/step; WRITE_SIZE==h proved HBM-level acks).
// SAFETY (R5 deadlocked on an assumed-mapping version of this): every wave
// ALSO publishes its h-slice as fire-and-forget SYSTEM-scope tagged u32
// words (R11-proven format) every step, issued before it can block. The sc0
// poll is bounded; on exhaustion the wave permanently switches to
// tag-verified sys loads of the mirror. Induction: mirror h_t is always
// issued during iteration t (post-load when fast, pre-fallback-load when
// not), so fallback consumers terminate. Worst case = slow pass, never hang.
// ig_gemm / final_linear unchanged (R14-proven).
// ---------------------------------------------------------------------------

typedef short short8 __attribute__((ext_vector_type(8)));
typedef float f32x4 __attribute__((ext_vector_type(4)));
typedef int int4v __attribute__((ext_vector_type(4)));

#define NB 128
#define NT 512
#define ND 512
#define NH 512
#define NG 1536  // 3H

__device__ __forceinline__ unsigned short f2bf(float f) {
  union { float f; unsigned u; } v; v.f = f;
  unsigned r = v.u + 0x7fffu + ((v.u >> 16) & 1u);  // RNE
  return (unsigned short)(r >> 16);
}
__device__ __forceinline__ float bf2f(unsigned short u) {
  union { unsigned u; float f; } v; v.u = ((unsigned)u) << 16; return v.f;
}
__device__ __forceinline__ float sigmoid_f(float x) {
  float e = __builtin_amdgcn_exp2f(-1.4426950408889634f * x);
  return __builtin_amdgcn_rcpf(1.0f + e);
}
__device__ __forceinline__ float tanh_f(float x) {
  float e = __builtin_amdgcn_exp2f(2.8853900817779268f * x);
  return 1.0f - 2.0f * __builtin_amdgcn_rcpf(1.0f + e);
}
__device__ __forceinline__ short8 pack8(float4 a, float4 b) {
  short8 s;
  s[0] = (short)f2bf(a.x); s[1] = (short)f2bf(a.y);
  s[2] = (short)f2bf(a.z); s[3] = (short)f2bf(a.w);
  s[4] = (short)f2bf(b.x); s[5] = (short)f2bf(b.y);
  s[6] = (short)f2bf(b.z); s[7] = (short)f2bf(b.w);
  return s;
}

// ---- sc0 (XCD-local L2) ring ops ------------------------------------------
__device__ __forceinline__ void load_h16_l2(const unsigned short* p, int4v a[16]) {
  asm volatile(
      "global_load_dwordx4 %0,  %16, off sc0\n\t"
      "global_load_dwordx4 %1,  %16, off offset:64 sc0\n\t"
      "global_load_dwordx4 %2,  %16, off offset:128 sc0\n\t"
      "global_load_dwordx4 %3,  %16, off offset:192 sc0\n\t"
      "global_load_dwordx4 %4,  %16, off offset:256 sc0\n\t"
      "global_load_dwordx4 %5,  %16, off offset:320 sc0\n\t"
      "global_load_dwordx4 %6,  %16, off offset:384 sc0\n\t"
      "global_load_dwordx4 %7,  %16, off offset:448 sc0\n\t"
      "global_load_dwordx4 %8,  %16, off offset:512 sc0\n\t"
      "global_load_dwordx4 %9,  %16, off offset:576 sc0\n\t"
      "global_load_dwordx4 %10, %16, off offset:640 sc0\n\t"
      "global_load_dwordx4 %11, %16, off offset:704 sc0\n\t"
      "global_load_dwordx4 %12, %16, off offset:768 sc0\n\t"
      "global_load_dwordx4 %13, %16, off offset:832 sc0\n\t"
      "global_load_dwordx4 %14, %16, off offset:896 sc0\n\t"
      "global_load_dwordx4 %15, %16, off offset:960 sc0\n\t"
      "s_waitcnt vmcnt(0)"
      : "=&v"(a[0]), "=&v"(a[1]), "=&v"(a[2]), "=&v"(a[3]),
        "=&v"(a[4]), "=&v"(a[5]), "=&v"(a[6]), "=&v"(a[7]),
        "=&v"(a[8]), "=&v"(a[9]), "=&v"(a[10]), "=&v"(a[11]),
        "=&v"(a[12]), "=&v"(a[13]), "=&v"(a[14]), "=&v"(a[15])
      : "v"(p)
      : "memory");
}

__device__ __forceinline__ void store_h4_l2(unsigned short* p, unsigned v0,
                                            unsigned v1, unsigned v2, unsigned v3) {
  asm volatile(
      "global_store_short %0, %1, off sc0\n\t"
      "global_store_short %0, %2, off offset:1024 sc0\n\t"
      "global_store_short %0, %3, off offset:2048 sc0\n\t"
      "global_store_short %0, %4, off offset:3072 sc0\n\t"
      "s_waitcnt vmcnt(0)"
      :
      : "v"(p), "v"(v0), "v"(v1), "v"(v2), "v"(v3)
      : "memory");
}

__device__ __forceinline__ unsigned poll_l2(const unsigned* p) {
  unsigned f;
  asm volatile(
      "global_load_dword %0, %1, off sc0\n\t"
      "s_waitcnt vmcnt(0)"
      : "=v"(f) : "v"(p) : "memory");
  return f;
}

__device__ __forceinline__ void flag_l2(unsigned* p, unsigned v) {
  asm volatile("global_store_dword %0, %1, off sc0"
               :: "v"(p), "v"(v) : "memory");
}

// ---- system-scope mirror ops (fallback path) ------------------------------
// 4 tagged u32 stores (rows erow..erow+3, stride 2048B), base +2 rows. NO drain.
__device__ __forceinline__ void mir4_sys(unsigned* p2, unsigned m0, unsigned m1,
                                         unsigned m2, unsigned m3) {
  asm volatile(
      "global_store_dword %0, %1, off offset:-4096 sc0 sc1\n\t"
      "global_store_dword %0, %2, off offset:-2048 sc0 sc1\n\t"
      "global_store_dword %0, %3, off sc0 sc1\n\t"
      "global_store_dword %0, %4, off offset:2048 sc0 sc1"
      :
      : "v"(p2), "v"(m0), "v"(m1), "v"(m2), "v"(m3)
      : "memory");
}

// 16 sys dwordx4 loads: 8 tagged chunks (j*128B and j*128B+16B). R11-proven.
__device__ __forceinline__ void load_t16x4_sys(const unsigned* p, int4v a[16]) {
  asm volatile(
      "global_load_dwordx4 %0,  %16, off sc0 sc1\n\t"
      "global_load_dwordx4 %1,  %16, off offset:16 sc0 sc1\n\t"
      "global_load_dwordx4 %2,  %16, off offset:128 sc0 sc1\n\t"
      "global_load_dwordx4 %3,  %16, off offset:144 sc0 sc1\n\t"
      "global_load_dwordx4 %4,  %16, off offset:256 sc0 sc1\n\t"
      "global_load_dwordx4 %5,  %16, off offset:272 sc0 sc1\n\t"
      "global_load_dwordx4 %6,  %16, off offset:384 sc0 sc1\n\t"
      "global_load_dwordx4 %7,  %16, off offset:400 sc0 sc1\n\t"
      "global_load_dwordx4 %8,  %16, off offset:512 sc0 sc1\n\t"
      "global_load_dwordx4 %9,  %16, off offset:528 sc0 sc1\n\t"
      "global_load_dwordx4 %10, %16, off offset:640 sc0 sc1\n\t"
      "global_load_dwordx4 %11, %16, off offset:656 sc0 sc1\n\t"
      "global_load_dwordx4 %12, %16, off offset:768 sc0 sc1\n\t"
      "global_load_dwordx4 %13, %16, off offset:784 sc0 sc1\n\t"
      "global_load_dwordx4 %14, %16, off offset:896 sc0 sc1\n\t"
      "global_load_dwordx4 %15, %16, off offset:912 sc0 sc1\n\t"
      "s_waitcnt vmcnt(0)"
      : "=&v"(a[0]), "=&v"(a[1]), "=&v"(a[2]), "=&v"(a[3]),
        "=&v"(a[4]), "=&v"(a[5]), "=&v"(a[6]), "=&v"(a[7]),
        "=&v"(a[8]), "=&v"(a[9]), "=&v"(a[10]), "=&v"(a[11]),
        "=&v"(a[12]), "=&v"(a[13]), "=&v"(a[14]), "=&v"(a[15])
      : "v"(p)
      : "memory");
}

// ---------------------------------------------------------------------------
// IG = x @ Wih^T + bias, bf16 out. M=65536, N=1536, K=512. (unchanged)
// ---------------------------------------------------------------------------
__global__ __launch_bounds__(256) void ig_gemm(
    const float* __restrict__ x, const float* __restrict__ Wih,
    const float* __restrict__ bias, unsigned short* __restrict__ IG) {
  __shared__ unsigned short As[128 * 40];
  __shared__ unsigned short Bs[128 * 40];
  const int tid = threadIdx.x;
  const int bm = blockIdx.x, bn = blockIdx.y;
  const int lane = tid & 63, w = tid >> 6;
  const int wm = w >> 1, wn = w & 1;
  const int l15 = lane & 15, q = lane >> 4;

  f32x4 acc[4][4] = {};

  for (int kt = 0; kt < 16; ++kt) {
    __syncthreads();
#pragma unroll
    for (int j = 0; j < 4; ++j) {
      int fi = tid + 256 * j;
      int row = fi >> 3, kq = fi & 7;
      float4 v = *(const float4*)(x + (size_t)(bm * 128 + row) * ND + kt * 32 + kq * 4);
      ushort4 s = {f2bf(v.x), f2bf(v.y), f2bf(v.z), f2bf(v.w)};
      *(ushort4*)&As[row * 40 + kq * 4] = s;
    }
#pragma unroll
    for (int j = 0; j < 4; ++j) {
      int fi = tid + 256 * j;
      int row = fi >> 3, kq = fi & 7;
      float4 v = *(const float4*)(Wih + (size_t)(bn * 128 + row) * ND + kt * 32 + kq * 4);
      ushort4 s = {f2bf(v.x), f2bf(v.y), f2bf(v.z), f2bf(v.w)};
      *(ushort4*)&Bs[row * 40 + kq * 4] = s;
    }
    __syncthreads();

    short8 af[4], bfv[4];
#pragma unroll
    for (int tm = 0; tm < 4; ++tm)
      af[tm] = *(const short8*)&As[(wm * 64 + tm * 16 + l15) * 40 + q * 8];
#pragma unroll
    for (int tn = 0; tn < 4; ++tn)
      bfv[tn] = *(const short8*)&Bs[(wn * 64 + tn * 16 + l15) * 40 + q * 8];
#pragma unroll
    for (int tm = 0; tm < 4; ++tm)
#pragma unroll
      for (int tn = 0; tn < 4; ++tn)
        acc[tm][tn] = __builtin_amdgcn_mfma_f32_16x16x32_bf16(af[tm], bfv[tn], acc[tm][tn], 0, 0, 0);
  }

#pragma unroll
  for (int tm = 0; tm < 4; ++tm) {
#pragma unroll
    for (int tn = 0; tn < 4; ++tn) {
      int col = bn * 128 + wn * 64 + tn * 16 + l15;
      float bb = bias[col];
#pragma unroll
      for (int i = 0; i < 4; ++i) {
        int row = bm * 128 + wm * 64 + tm * 16 + q * 4 + i;
        IG[(size_t)row * NG + col] = f2bf(acc[tm][tn][i] + bb);
      }
    }
  }
}

// ---------------------------------------------------------------------------
// Persistent GRU recurrence. 512 blocks x 256 threads; only the 64 blocks on
// XCD 0 (hardware-verified) claim ring roles; the rest exit immediately.
// Role r: g=r>>4 (group of 32 batch rows), c=r&15 (chunk of 32 h-cols).
// hflags[((g*2+wm)*16+c)*2+wn] = step published (sc0, XCD-0 L2).
// mir[t&1]: sys-scope tagged u32 (bf16<<16|t) mirror for the fallback path.
// ---------------------------------------------------------------------------
template <bool USE_IG>
__global__ __launch_bounds__(256, 1) void gru_rec(
    const float* __restrict__ x, const float* __restrict__ Wih,
    const float* __restrict__ Whh, const float* __restrict__ bias,
    const float* __restrict__ bn, const unsigned short* __restrict__ IG,
    unsigned short* __restrict__ hbuf, unsigned* __restrict__ mir,
    unsigned* __restrict__ hflags, unsigned* __restrict__ ctrs,
    float* __restrict__ hfin) {
  __shared__ int stick;
  const int tid = threadIdx.x;

  unsigned myxcd;
  asm volatile("s_getreg_b32 %0, hwreg(HW_REG_XCC_ID)" : "=s"(myxcd));
  if (tid == 0) {
    int tk = -1;
    if (myxcd == 0) tk = (int)atomicAdd(&ctrs[0], 1u);
    stick = tk;
  }
  __syncthreads();
  const int r = stick;
  if (r < 0 || r >= 64) return;  // not a ring block

  const int lane = tid & 63;
  const int w = tid >> 6;
  const int wm = w >> 1, wn = w & 1;
  const int l15 = lane & 15, q = lane >> 4;
  const int g = r >> 4;            // 4 groups of 32 batch rows
  const int c = r & 15;            // 16 col-chunks of 32
  const int b0 = g * 32;
  const int col = c * 32 + wn * 16 + l15;  // this lane's h column
  const int mrow = b0 + wm * 16 + l15;     // A-fragment batch row
  const int erow = b0 + wm * 16 + q * 4;   // C-layout batch row base

  unsigned* const myflag = hflags + ((g * 2 + wm) * 16 + c) * 2 + wn;
  const unsigned* const pollbase = hflags + (g * 2 + wm) * 32;  // 32 flags

  // Whh B-fragments -> registers: 3 gates x 16 k-chunks (192 VGPRs)
  short8 bfr[3][16];
#pragma unroll
  for (int gt = 0; gt < 3; ++gt) {
    const float* src = Whh + (size_t)(gt * NH + col) * NH + q * 8;
#pragma unroll
    for (int kk = 0; kk < 16; ++kk) {
      float4 v0 = *(const float4*)(src + kk * 32);
      float4 v1 = *(const float4*)(src + kk * 32 + 4);
      bfr[gt][kk] = pack8(v0, v1);
    }
  }

  float bi_r = 0.f, bi_z = 0.f, bi_n = 0.f;
  if (!USE_IG) {
    bi_r = bias[col];
    bi_z = bias[NH + col];
    bi_n = bias[2 * NH + col];
  }
  const float bnv = bn[col];

  float hreg[4] = {0.f, 0.f, 0.f, 0.f};
  unsigned msv[4] = {0u, 0u, 0u, 0u};  // tagged mirror words of h_t

  unsigned short* const hb0 = hbuf;
  unsigned short* const hb1 = hbuf + NB * NH;
  unsigned* const mb0 = mir;
  unsigned* const mb1 = mir + NB * NH;

  bool fastm = true;

  for (int t = 0; t < NT; ++t) {
    const unsigned short* hcur = (t & 1) ? hb1 : hb0;
    unsigned short* hnxt = (t & 1) ? hb0 : hb1;
    unsigned* mcur = (t & 1) ? mb1 : mb0;

    int4v araw[16];
    if (t > 0) {
      unsigned* mp2 = mcur + (size_t)(erow + 2) * NH + col;  // mirror base(+2 rows)
      if (fastm) {
        // sc0 poll at XCD-0 L2; bounded (2^20) so a broken sc0 cannot hang us
        bool esc = false;
        if (lane < 32) {
          const unsigned* fp = pollbase + lane;
          unsigned f = poll_l2(fp);
          int tr = 0;
          while ((int)f < t) {
            if (++tr > (1 << 20)) { esc = true; break; }
            f = poll_l2(fp);
          }
        }
        if (__any(esc)) fastm = false;  // sticky fallback
      }
      if (fastm) {
        // fast: sc0 h load (XCD-0 L2, fresh by construction), then issue
        // this wave's mirror of h_t (acks retire under MFMA+gates).
        load_h16_l2(hcur + (size_t)mrow * NH + q * 8, araw);
        mir4_sys(mp2, msv[0], msv[1], msv[2], msv[3]);
      } else {
        // fallback: publish own mirror FIRST (so peers can't starve), then
        // tag-verified sys loads of the mirror (terminates: every wave
        // issues its mirror during iteration t before blocking).
        mir4_sys(mp2, msv[0], msv[1], msv[2], msv[3]);
        const unsigned tt = (unsigned)t;
#pragma unroll
        for (int half = 0; half < 2; ++half) {
          const unsigned* hp = mcur + (size_t)mrow * NH + half * 256 + q * 8;
          int4v a16[16];
          unsigned bad;
          do {
            load_t16x4_sys(hp, a16);
            bad = 0;
#pragma unroll
            for (int i = 0; i < 16; ++i)
#pragma unroll
              for (int j = 0; j < 4; ++j)
                bad |= ((unsigned)a16[i][j] ^ tt) & 0xffffu;
          } while (__builtin_expect(bad != 0, 0));
#pragma unroll
          for (int j = 0; j < 8; ++j) {
            const int4v dlo = a16[2 * j];
            const int4v dhi = a16[2 * j + 1];
            unsigned w0 = __builtin_amdgcn_perm((unsigned)dlo[1], (unsigned)dlo[0], 0x07060302u);
            unsigned w1 = __builtin_amdgcn_perm((unsigned)dlo[3], (unsigned)dlo[2], 0x07060302u);
            unsigned w2 = __builtin_amdgcn_perm((unsigned)dhi[1], (unsigned)dhi[0], 0x07060302u);
            unsigned w3 = __builtin_amdgcn_perm((unsigned)dhi[3], (unsigned)dhi[2], 0x07060302u);
            araw[half * 8 + j] = (int4v){(int)w0, (int)w1, (int)w2, (int)w3};
          }
        }
      }
    } else {
      // h_0 = 0: no poll, no load, no mirror
#pragma unroll
      for (int kk = 0; kk < 16; ++kk) araw[kk] = (int4v){0, 0, 0, 0};
    }

    // IG loads (plain cached; IG fully materialized by the prior kernel)
    float igr[4], igz[4], ign[4];
    if (USE_IG) {
#pragma unroll
      for (int i = 0; i < 4; ++i) {
        const size_t base = ((size_t)(erow + i) * NT + t) * NG + col;
        igr[i] = bf2f(IG[base]);
        igz[i] = bf2f(IG[base + NH]);
        ign[i] = bf2f(IG[base + 2 * NH]);
      }
    }

    f32x4 ar = {0.f, 0.f, 0.f, 0.f};
    f32x4 az = {0.f, 0.f, 0.f, 0.f};
    f32x4 an = {0.f, 0.f, 0.f, 0.f};
    f32x4 ai = {0.f, 0.f, 0.f, 0.f};
#pragma unroll
    for (int kk = 0; kk < 16; ++kk) {
      short8 afk = __builtin_bit_cast(short8, araw[kk]);
      ar = __builtin_amdgcn_mfma_f32_16x16x32_bf16(afk, bfr[0][kk], ar, 0, 0, 0);
      az = __builtin_amdgcn_mfma_f32_16x16x32_bf16(afk, bfr[1][kk], az, 0, 0, 0);
      an = __builtin_amdgcn_mfma_f32_16x16x32_bf16(afk, bfr[2][kk], an, 0, 0, 0);
      if (!USE_IG) {
        const float* xp = x + ((size_t)mrow * NT + t) * ND + kk * 32 + q * 8;
        short8 xa = pack8(*(const float4*)xp, *(const float4*)(xp + 4));
#pragma unroll
        for (int gt = 0; gt < 3; ++gt) {
          const float* wp = Wih + (size_t)(gt * NH + col) * ND + kk * 32 + q * 8;
          short8 wf = pack8(*(const float4*)wp, *(const float4*)(wp + 4));
          if (gt == 0) ar = __builtin_amdgcn_mfma_f32_16x16x32_bf16(xa, wf, ar, 0, 0, 0);
          if (gt == 1) az = __builtin_amdgcn_mfma_f32_16x16x32_bf16(xa, wf, az, 0, 0, 0);
          if (gt == 2) ai = __builtin_amdgcn_mfma_f32_16x16x32_bf16(xa, wf, ai, 0, 0, 0);
        }
      }
    }

    // gates + h update; sc0 store -> drain(L2) -> sc0 flag; prep mirror words
    unsigned sv[4];
#pragma unroll
    for (int i = 0; i < 4; ++i) {
      float xr = USE_IG ? (ar[i] + igr[i]) : (ar[i] + bi_r);
      float xz = USE_IG ? (az[i] + igz[i]) : (az[i] + bi_z);
      float xin = USE_IG ? ign[i] : (ai[i] + bi_n);
      float rr = sigmoid_f(xr);
      float z = sigmoid_f(xz);
      float n = tanh_f(xin + rr * (an[i] + bnv));
      float hn2 = (1.f - z) * n + z * hreg[i];
      hreg[i] = hn2;
      sv[i] = (unsigned)f2bf(hn2);
      msv[i] = (sv[i] << 16) | (unsigned)(t + 1);  // tagged mirror of h_{t+1}
      if (t == NT - 1) hfin[(size_t)(erow + i) * NH + col] = hn2;
    }
    if (t != NT - 1) {
      store_h4_l2(hnxt + (size_t)erow * NH + col, sv[0], sv[1], sv[2], sv[3]);
      if (lane == 0) flag_l2(myflag, (unsigned)(t + 1));
    }
  }
}

// ---------------------------------------------------------------------------
// out = h_T @ Wlin^T + blin; mu = cols [0,256), logvar = cols [256,512).
// ---------------------------------------------------------------------------
__global__ __launch_bounds__(256) void final_linear(
    const float* __restrict__ hfin, const float* __restrict__ Wlin,
    const float* __restrict__ blin, float* __restrict__ out) {
  __shared__ float sh[16 * 516];
  const int tid = threadIdx.x;
  const int b0 = blockIdx.y * 16, o0 = blockIdx.x * 16;

  for (int j = tid; j < 16 * 128; j += 256) {
    int row = j >> 7, kq = j & 127;
    *(float4*)&sh[row * 516 + kq * 4] =
        *(const float4*)(hfin + (size_t)(b0 + row) * NH + kq * 4);
  }
  __syncthreads();

  const int bi = tid & 15, oi = tid >> 4;
  const int o = o0 + oi;
  const float4* wp = (const float4*)(Wlin + (size_t)o * NH);
  float4 a4 = {0.f, 0.f, 0.f, 0.f};
  for (int k4 = 0; k4 < 128; ++k4) {
    float4 wv = wp[k4];
    float4 hv = *(const float4*)&sh[bi * 516 + k4 * 4];
    a4.x += wv.x * hv.x; a4.y += wv.y * hv.y;
    a4.z += wv.z * hv.z; a4.w += wv.w * hv.w;
  }
  float v = a4.x + a4.y + a4.z + a4.w + blin[o];
  int b = b0 + bi;
  if (o < 256) out[b * 256 + o] = v;
  else out[32768 + b * 256 + (o - 256)] = v;
}

// ---------------------------------------------------------------------------
extern "C" void kernel_launch(void* const* d_in, const int* in_sizes, int n_in,
                              void* d_out, int out_size, void* d_ws, size_t ws_size,
                              hipStream_t stream) {
  const float* x    = (const float*)d_in[0];
  const float* Wih  = (const float*)d_in[1];
  const float* Whh  = (const float*)d_in[2];
  const float* bias = (const float*)d_in[3];
  const float* bn   = (const float*)d_in[4];
  const float* Wlin = (const float*)d_in[5];
  const float* blin = (const float*)d_in[6];
  float* out = (float*)d_out;

  char* ws = (char*)d_ws;
  // layout: [hbuf 262144][mir 524288][hflags 1024][ctrs 256][hfin 262144][IG]
  unsigned short* hbuf = (unsigned short*)ws;
  unsigned* mir        = (unsigned*)(ws + 262144);
  unsigned* hflags     = (unsigned*)(ws + 786432);
  unsigned* ctrs       = (unsigned*)(ws + 787456);
  float* hfin          = (float*)(ws + 787712);
  unsigned short* IG   = (unsigned short*)(ws + 1049856);
  const size_t need_min = 1049856;
  const size_t need_ig  = 1049856 + (size_t)NB * NT * NG * 2;  // ~203 MB
  if (ws_size < need_min) return;

  // zero mirror (tags), hflags, ctrs. hbuf needs no init (h_0 in registers).
  hipMemsetAsync(ws + 262144, 0, 524288 + 1024 + 256, stream);

  const bool useIG = (ws_size >= need_ig);
  if (useIG) {
    ig_gemm<<<dim3(512, 12), 256, 0, stream>>>(x, Wih, bias, IG);
    gru_rec<true><<<512, 256, 0, stream>>>(x, Wih, Whh, bias, bn, IG,
                                           hbuf, mir, hflags, ctrs, hfin);
  } else {
    gru_rec<false><<<512, 256, 0, stream>>>(x, Wih, Whh, bias, bn, nullptr,
                                            hbuf, mir, hflags, ctrs, hfin);
  }
  final_linear<<<dim3(32, 8), 256, 0, stream>>>(hfin, Wlin, blin, out);
}

// Round 13
// 4328.959 us; speedup vs baseline: 57.1928x; 57.1928x over previous
//
#include <hip/hip_runtime.h>
#include <stdint.h>

// ---------------------------------------------------------------------------
// GRU encoder (B=128,T=512,D=512,H=512,L=256), MI355X gfx950.
//
// R17: R12's 2-RT ring protocol (store tagged h + flag, NO drain; consumer:
// flag poll -> ONE tagged load batch -> tag verify) — de-spilled by moving
// the Whh fragments from 192 VGPRs into 96KB of LDS.
// Evidence trail:
//  - R16 proved sc0 is SE-scope (bounded poll exhausted; fallback fired):
//    no scope between SE and device; R14 proved device==system (write-through
//    to HBM). Cross-fabric RT ~2000cy is a hardware constant -> attack RT
//    COUNT, not latency.
//  - R4 pays 3 serial RTs/step (drain, poll, load) = 9400cy/step.
//  - R12 removed the drain RT but spilled (128 tagged-load VGPRs + 192 bfr
//    VGPRs): VGPR capped 224, scratch traffic, 18k cy/step. Whh->LDS frees
//    the budget; predicted ~200 VGPR, no scratch.
// LDS layout: Blds[gate][kk][q][colIdx] = 16B fragments; a wave's read is
// 1KB contiguous (ideal). Shared by the wm-paired waves (same cols).
// Protocol correctness (R11/R12/R13-proven induction): tag-verified read of
// h_t proves all waves stored h_t, hence finished reading h_{t-1}, hence
// overwriting buffer parity (t-1) with h_{t+1} is safe. Flag may overtake
// data (no drain) -> tags catch it -> rare 1-RT retry. Deadlock-free:
// stores unconditional, tags eventually match.
// hbuf = tagged u32 (bf16<<16 | step), both buffers memset 0 (tags 1..511).
// ig_gemm / final_linear unchanged (proven).
// ---------------------------------------------------------------------------

typedef short short8 __attribute__((ext_vector_type(8)));
typedef float f32x4 __attribute__((ext_vector_type(4)));
typedef int int4v __attribute__((ext_vector_type(4)));

#define NB 128
#define NT 512
#define ND 512
#define NH 512
#define NG 1536  // 3H

__device__ __forceinline__ unsigned short f2bf(float f) {
  union { float f; unsigned u; } v; v.f = f;
  unsigned r = v.u + 0x7fffu + ((v.u >> 16) & 1u);  // RNE
  return (unsigned short)(r >> 16);
}
__device__ __forceinline__ float bf2f(unsigned short u) {
  union { unsigned u; float f; } v; v.u = ((unsigned)u) << 16; return v.f;
}
__device__ __forceinline__ float sigmoid_f(float x) {
  float e = __builtin_amdgcn_exp2f(-1.4426950408889634f * x);
  return __builtin_amdgcn_rcpf(1.0f + e);
}
__device__ __forceinline__ float tanh_f(float x) {
  float e = __builtin_amdgcn_exp2f(2.8853900817779268f * x);
  return 1.0f - 2.0f * __builtin_amdgcn_rcpf(1.0f + e);
}
__device__ __forceinline__ short8 pack8(float4 a, float4 b) {
  short8 s;
  s[0] = (short)f2bf(a.x); s[1] = (short)f2bf(a.y);
  s[2] = (short)f2bf(a.z); s[3] = (short)f2bf(a.w);
  s[4] = (short)f2bf(b.x); s[5] = (short)f2bf(b.y);
  s[6] = (short)f2bf(b.z); s[7] = (short)f2bf(b.w);
  return s;
}

// 32 coherent dwordx4 loads (lane's 16 tagged chunks: byte kk*128 and
// kk*128+16) with ONE vmcnt(0). p = lane u32 pointer (incl. +q*8). (R12)
__device__ __forceinline__ void load_t32(const unsigned* p, int4v a[32]) {
  asm volatile(
      "global_load_dwordx4 %0,  %32, off sc0 sc1\n\t"
      "global_load_dwordx4 %1,  %32, off offset:16 sc0 sc1\n\t"
      "global_load_dwordx4 %2,  %32, off offset:128 sc0 sc1\n\t"
      "global_load_dwordx4 %3,  %32, off offset:144 sc0 sc1\n\t"
      "global_load_dwordx4 %4,  %32, off offset:256 sc0 sc1\n\t"
      "global_load_dwordx4 %5,  %32, off offset:272 sc0 sc1\n\t"
      "global_load_dwordx4 %6,  %32, off offset:384 sc0 sc1\n\t"
      "global_load_dwordx4 %7,  %32, off offset:400 sc0 sc1\n\t"
      "global_load_dwordx4 %8,  %32, off offset:512 sc0 sc1\n\t"
      "global_load_dwordx4 %9,  %32, off offset:528 sc0 sc1\n\t"
      "global_load_dwordx4 %10, %32, off offset:640 sc0 sc1\n\t"
      "global_load_dwordx4 %11, %32, off offset:656 sc0 sc1\n\t"
      "global_load_dwordx4 %12, %32, off offset:768 sc0 sc1\n\t"
      "global_load_dwordx4 %13, %32, off offset:784 sc0 sc1\n\t"
      "global_load_dwordx4 %14, %32, off offset:896 sc0 sc1\n\t"
      "global_load_dwordx4 %15, %32, off offset:912 sc0 sc1\n\t"
      "global_load_dwordx4 %16, %32, off offset:1024 sc0 sc1\n\t"
      "global_load_dwordx4 %17, %32, off offset:1040 sc0 sc1\n\t"
      "global_load_dwordx4 %18, %32, off offset:1152 sc0 sc1\n\t"
      "global_load_dwordx4 %19, %32, off offset:1168 sc0 sc1\n\t"
      "global_load_dwordx4 %20, %32, off offset:1280 sc0 sc1\n\t"
      "global_load_dwordx4 %21, %32, off offset:1296 sc0 sc1\n\t"
      "global_load_dwordx4 %22, %32, off offset:1408 sc0 sc1\n\t"
      "global_load_dwordx4 %23, %32, off offset:1424 sc0 sc1\n\t"
      "global_load_dwordx4 %24, %32, off offset:1536 sc0 sc1\n\t"
      "global_load_dwordx4 %25, %32, off offset:1552 sc0 sc1\n\t"
      "global_load_dwordx4 %26, %32, off offset:1664 sc0 sc1\n\t"
      "global_load_dwordx4 %27, %32, off offset:1680 sc0 sc1\n\t"
      "global_load_dwordx4 %28, %32, off offset:1792 sc0 sc1\n\t"
      "global_load_dwordx4 %29, %32, off offset:1808 sc0 sc1\n\t"
      "global_load_dwordx4 %30, %32, off offset:1920 sc0 sc1\n\t"
      "global_load_dwordx4 %31, %32, off offset:1936 sc0 sc1\n\t"
      "s_waitcnt vmcnt(0)"
      : "=&v"(a[0]), "=&v"(a[1]), "=&v"(a[2]), "=&v"(a[3]),
        "=&v"(a[4]), "=&v"(a[5]), "=&v"(a[6]), "=&v"(a[7]),
        "=&v"(a[8]), "=&v"(a[9]), "=&v"(a[10]), "=&v"(a[11]),
        "=&v"(a[12]), "=&v"(a[13]), "=&v"(a[14]), "=&v"(a[15]),
        "=&v"(a[16]), "=&v"(a[17]), "=&v"(a[18]), "=&v"(a[19]),
        "=&v"(a[20]), "=&v"(a[21]), "=&v"(a[22]), "=&v"(a[23]),
        "=&v"(a[24]), "=&v"(a[25]), "=&v"(a[26]), "=&v"(a[27]),
        "=&v"(a[28]), "=&v"(a[29]), "=&v"(a[30]), "=&v"(a[31])
      : "v"(p)
      : "memory");
}

// 4 tagged dword stores (rows erow..erow+3, stride 2048B), base +2 rows so
// 13-bit signed offsets reach all 4. NO drain. (R12-proven)
__device__ __forceinline__ void store_t4(unsigned* p2, unsigned v0,
                                         unsigned v1, unsigned v2, unsigned v3) {
  asm volatile(
      "global_store_dword %0, %1, off offset:-4096 sc0 sc1\n\t"
      "global_store_dword %0, %2, off offset:-2048 sc0 sc1\n\t"
      "global_store_dword %0, %3, off sc0 sc1\n\t"
      "global_store_dword %0, %4, off offset:2048 sc0 sc1"
      :
      : "v"(p2), "v"(v0), "v"(v1), "v"(v2), "v"(v3)
      : "memory");
}

__device__ __forceinline__ unsigned poll_load(const unsigned* p) {
  unsigned f;
  asm volatile(
      "global_load_dword %0, %1, off sc0 sc1\n\t"
      "s_waitcnt vmcnt(0)"
      : "=v"(f) : "v"(p) : "memory");
  return f;
}

__device__ __forceinline__ void flag_store(unsigned* p, unsigned v) {
  asm volatile("global_store_dword %0, %1, off sc0 sc1"
               :: "v"(p), "v"(v) : "memory");
}

// ---------------------------------------------------------------------------
// IG = x @ Wih^T + bias, bf16 out. M=65536, N=1536, K=512. (unchanged)
// ---------------------------------------------------------------------------
__global__ __launch_bounds__(256) void ig_gemm(
    const float* __restrict__ x, const float* __restrict__ Wih,
    const float* __restrict__ bias, unsigned short* __restrict__ IG) {
  __shared__ unsigned short As[128 * 40];
  __shared__ unsigned short Bs[128 * 40];
  const int tid = threadIdx.x;
  const int bm = blockIdx.x, bn = blockIdx.y;
  const int lane = tid & 63, w = tid >> 6;
  const int wm = w >> 1, wn = w & 1;
  const int l15 = lane & 15, q = lane >> 4;

  f32x4 acc[4][4] = {};

  for (int kt = 0; kt < 16; ++kt) {
    __syncthreads();
#pragma unroll
    for (int j = 0; j < 4; ++j) {
      int fi = tid + 256 * j;
      int row = fi >> 3, kq = fi & 7;
      float4 v = *(const float4*)(x + (size_t)(bm * 128 + row) * ND + kt * 32 + kq * 4);
      ushort4 s = {f2bf(v.x), f2bf(v.y), f2bf(v.z), f2bf(v.w)};
      *(ushort4*)&As[row * 40 + kq * 4] = s;
    }
#pragma unroll
    for (int j = 0; j < 4; ++j) {
      int fi = tid + 256 * j;
      int row = fi >> 3, kq = fi & 7;
      float4 v = *(const float4*)(Wih + (size_t)(bn * 128 + row) * ND + kt * 32 + kq * 4);
      ushort4 s = {f2bf(v.x), f2bf(v.y), f2bf(v.z), f2bf(v.w)};
      *(ushort4*)&Bs[row * 40 + kq * 4] = s;
    }
    __syncthreads();

    short8 af[4], bfv[4];
#pragma unroll
    for (int tm = 0; tm < 4; ++tm)
      af[tm] = *(const short8*)&As[(wm * 64 + tm * 16 + l15) * 40 + q * 8];
#pragma unroll
    for (int tn = 0; tn < 4; ++tn)
      bfv[tn] = *(const short8*)&Bs[(wn * 64 + tn * 16 + l15) * 40 + q * 8];
#pragma unroll
    for (int tm = 0; tm < 4; ++tm)
#pragma unroll
      for (int tn = 0; tn < 4; ++tn)
        acc[tm][tn] = __builtin_amdgcn_mfma_f32_16x16x32_bf16(af[tm], bfv[tn], acc[tm][tn], 0, 0, 0);
  }

#pragma unroll
  for (int tm = 0; tm < 4; ++tm) {
#pragma unroll
    for (int tn = 0; tn < 4; ++tn) {
      int col = bn * 128 + wn * 64 + tn * 16 + l15;
      float bb = bias[col];
#pragma unroll
      for (int i = 0; i < 4; ++i) {
        int row = bm * 128 + wm * 64 + tm * 16 + q * 4 + i;
        IG[(size_t)row * NG + col] = f2bf(acc[tm][tn][i] + bb);
      }
    }
  }
}

// ---------------------------------------------------------------------------
// Persistent GRU recurrence. 64 blocks x 256 threads. (R4 topology)
// block = (group g of 32 batch rows, chunk c of 32 h-cols).
// wave (wm,wn): rows [b0+wm*16,+16), cols [c*32+wn*16,+16).
// Whh fragments live in LDS: Blds[((gate*16+kk)*4+q)*32 + colIdx] (16B each).
// h buffers: u32 tagged (bf16<<16 | step). flags: per-producer-wave.
// ---------------------------------------------------------------------------
template <bool USE_IG>
__global__ __launch_bounds__(256, 1) void gru_rec(
    const float* __restrict__ x, const float* __restrict__ Wih,
    const float* __restrict__ Whh, const float* __restrict__ bias,
    const float* __restrict__ bn, const unsigned short* __restrict__ IG,
    unsigned* __restrict__ hbuf, unsigned* __restrict__ flags,
    float* __restrict__ hfin) {
  __shared__ short8 Blds[3 * 16 * 4 * 32];  // 96 KB of Whh bf16 fragments

  const int tid = threadIdx.x;
  const int lane = tid & 63;
  const int w = tid >> 6;
  const int wm = w >> 1, wn = w & 1;
  const int l15 = lane & 15, q = lane >> 4;
  const int g = blockIdx.x >> 4;   // 4 groups
  const int c = blockIdx.x & 15;   // 16 col-chunks of 32
  const int b0 = g * 32;
  const int col = c * 32 + wn * 16 + l15;  // this lane's h column
  const int mrow = b0 + wm * 16 + l15;     // A-fragment batch row
  const int erow = b0 + wm * 16 + q * 4;   // C-layout batch row base
  const int ci = wn * 16 + l15;            // LDS col index

  unsigned* const myflag = flags + ((g * 2 + wm) * 16 + c) * 2 + wn;
  const unsigned* const pollbase = flags + (g * 2 + wm) * 32;  // 32 flags

  // Stage Whh fragments -> LDS (once). fid: gate=fid/2048, kk=(fid%2048)/128,
  // q2=(fid%128)/32, colIdx=fid%32.
#pragma unroll
  for (int j = 0; j < 24; ++j) {
    int fid = tid + 256 * j;
    int gate = fid >> 11;
    int rem = fid & 2047;
    int kk = rem >> 7;
    int q2 = (rem >> 5) & 3;
    int colIdx = rem & 31;
    const float* src = Whh + (size_t)(gate * NH + c * 32 + colIdx) * NH + kk * 32 + q2 * 8;
    Blds[((gate * 16 + kk) * 4 + q2) * 32 + colIdx] =
        pack8(*(const float4*)src, *(const float4*)(src + 4));
  }
  __syncthreads();

  float bi_r = 0.f, bi_z = 0.f, bi_n = 0.f;
  if (!USE_IG) {
    bi_r = bias[col];
    bi_z = bias[NH + col];
    bi_n = bias[2 * NH + col];
  }
  const float bnv = bn[col];

  float hreg[4] = {0.f, 0.f, 0.f, 0.f};

  unsigned* const hb0 = hbuf;
  unsigned* const hb1 = hbuf + NB * NH;

  for (int t = 0; t < NT; ++t) {
    const unsigned* hcur = (t & 1) ? hb1 : hb0;
    unsigned* hnxt = (t & 1) ? hb0 : hb1;

    int4v a[32];
    if (t > 0) {
      // 1) cheap flag gate; first poll's vmcnt(0) also absorbs my own
      //    outstanding tagged stores + flag store (overlapped drain).
      if (lane < 32) {
        const unsigned* fp = pollbase + lane;
        unsigned f = poll_load(fp);
        while ((int)f < t) f = poll_load(fp);
      }
      // 2) one-RT tagged load + verify; retry rare (flag/data issued
      //    back-to-back; poll+load adds >= 2 RTs of slack).
      const unsigned* hp = hcur + (size_t)mrow * NH + q * 8;
      const unsigned tt = (unsigned)t;
      unsigned bad;
      do {
        load_t32(hp, a);
        bad = 0;
#pragma unroll
        for (int i = 0; i < 32; ++i) {
#pragma unroll
          for (int j = 0; j < 4; ++j)
            bad |= ((unsigned)a[i][j] ^ tt) & 0xffffu;
        }
      } while (__builtin_expect(bad != 0, 0));
    } else {
#pragma unroll
      for (int i = 0; i < 32; ++i) a[i] = (int4v){0, 0, 0, 0};
    }

    // IG loads (plain cached), after verify; hide under repack+MFMA.
    float igr[4], igz[4], ign[4];
    if (USE_IG) {
#pragma unroll
      for (int i = 0; i < 4; ++i) {
        const size_t base = ((size_t)(erow + i) * NT + t) * NG + col;
        igr[i] = bf2f(IG[base]);
        igz[i] = bf2f(IG[base + NH]);
        ign[i] = bf2f(IG[base + 2 * NH]);
      }
    }

    f32x4 ar = {0.f, 0.f, 0.f, 0.f};
    f32x4 az = {0.f, 0.f, 0.f, 0.f};
    f32x4 an = {0.f, 0.f, 0.f, 0.f};
    f32x4 ai = {0.f, 0.f, 0.f, 0.f};
#pragma unroll
    for (int kk = 0; kk < 16; ++kk) {
      // repack tagged dwords (value in hi16) -> bf16 short8 fragment
      const int4v dlo = a[2 * kk];
      const int4v dhi = a[2 * kk + 1];
      unsigned w0 = __builtin_amdgcn_perm((unsigned)dlo[1], (unsigned)dlo[0], 0x07060302u);
      unsigned w1 = __builtin_amdgcn_perm((unsigned)dlo[3], (unsigned)dlo[2], 0x07060302u);
      unsigned w2 = __builtin_amdgcn_perm((unsigned)dhi[1], (unsigned)dhi[0], 0x07060302u);
      unsigned w3 = __builtin_amdgcn_perm((unsigned)dhi[3], (unsigned)dhi[2], 0x07060302u);
      int4v wv = {(int)w0, (int)w1, (int)w2, (int)w3};
      short8 afk = __builtin_bit_cast(short8, wv);

      const short8 br = Blds[((0 * 16 + kk) * 4 + q) * 32 + ci];
      const short8 bz = Blds[((1 * 16 + kk) * 4 + q) * 32 + ci];
      const short8 bnn = Blds[((2 * 16 + kk) * 4 + q) * 32 + ci];
      ar = __builtin_amdgcn_mfma_f32_16x16x32_bf16(afk, br, ar, 0, 0, 0);
      az = __builtin_amdgcn_mfma_f32_16x16x32_bf16(afk, bz, az, 0, 0, 0);
      an = __builtin_amdgcn_mfma_f32_16x16x32_bf16(afk, bnn, an, 0, 0, 0);
      if (!USE_IG) {
        const float* xp = x + ((size_t)mrow * NT + t) * ND + kk * 32 + q * 8;
        short8 xa = pack8(*(const float4*)xp, *(const float4*)(xp + 4));
#pragma unroll
        for (int gt = 0; gt < 3; ++gt) {
          const float* wp = Wih + (size_t)(gt * NH + col) * ND + kk * 32 + q * 8;
          short8 wf = pack8(*(const float4*)wp, *(const float4*)(wp + 4));
          if (gt == 0) ar = __builtin_amdgcn_mfma_f32_16x16x32_bf16(xa, wf, ar, 0, 0, 0);
          if (gt == 1) az = __builtin_amdgcn_mfma_f32_16x16x32_bf16(xa, wf, az, 0, 0, 0);
          if (gt == 2) ai = __builtin_amdgcn_mfma_f32_16x16x32_bf16(xa, wf, ai, 0, 0, 0);
        }
      }
    }

    // gates + h update; tagged stores (no drain) then flag (no drain)
    unsigned sv[4];
#pragma unroll
    for (int i = 0; i < 4; ++i) {
      float xr = USE_IG ? (ar[i] + igr[i]) : (ar[i] + bi_r);
      float xz = USE_IG ? (az[i] + igz[i]) : (az[i] + bi_z);
      float xin = USE_IG ? ign[i] : (ai[i] + bi_n);
      float r = sigmoid_f(xr);
      float z = sigmoid_f(xz);
      float n = tanh_f(xin + r * (an[i] + bnv));
      float hn2 = (1.f - z) * n + z * hreg[i];
      hreg[i] = hn2;
      sv[i] = ((unsigned)f2bf(hn2) << 16) | (unsigned)(t + 1);
      if (t == NT - 1) hfin[(size_t)(erow + i) * NH + col] = hn2;
    }
    if (t != NT - 1) {
      unsigned* sp2 = hnxt + (size_t)(erow + 2) * NH + col;  // +2-row base
      store_t4(sp2, sv[0], sv[1], sv[2], sv[3]);
      if (lane == 0) flag_store(myflag, (unsigned)(t + 1));
    }
  }
}

// ---------------------------------------------------------------------------
// out = h_T @ Wlin^T + blin; mu = cols [0,256), logvar = cols [256,512).
// ---------------------------------------------------------------------------
__global__ __launch_bounds__(256) void final_linear(
    const float* __restrict__ hfin, const float* __restrict__ Wlin,
    const float* __restrict__ blin, float* __restrict__ out) {
  __shared__ float sh[16 * 516];
  const int tid = threadIdx.x;
  const int b0 = blockIdx.y * 16, o0 = blockIdx.x * 16;

  for (int j = tid; j < 16 * 128; j += 256) {
    int row = j >> 7, kq = j & 127;
    *(float4*)&sh[row * 516 + kq * 4] =
        *(const float4*)(hfin + (size_t)(b0 + row) * NH + kq * 4);
  }
  __syncthreads();

  const int bi = tid & 15, oi = tid >> 4;
  const int o = o0 + oi;
  const float4* wp = (const float4*)(Wlin + (size_t)o * NH);
  float4 a4 = {0.f, 0.f, 0.f, 0.f};
  for (int k4 = 0; k4 < 128; ++k4) {
    float4 wv = wp[k4];
    float4 hv = *(const float4*)&sh[bi * 516 + k4 * 4];
    a4.x += wv.x * hv.x; a4.y += wv.y * hv.y;
    a4.z += wv.z * hv.z; a4.w += wv.w * hv.w;
  }
  float v = a4.x + a4.y + a4.z + a4.w + blin[o];
  int b = b0 + bi;
  if (o < 256) out[b * 256 + o] = v;
  else out[32768 + b * 256 + (o - 256)] = v;
}

// ---------------------------------------------------------------------------
extern "C" void kernel_launch(void* const* d_in, const int* in_sizes, int n_in,
                              void* d_out, int out_size, void* d_ws, size_t ws_size,
                              hipStream_t stream) {
  const float* x    = (const float*)d_in[0];
  const float* Wih  = (const float*)d_in[1];
  const float* Whh  = (const float*)d_in[2];
  const float* bias = (const float*)d_in[3];
  const float* bn   = (const float*)d_in[4];
  const float* Wlin = (const float*)d_in[5];
  const float* blin = (const float*)d_in[6];
  float* out = (float*)d_out;

  char* ws = (char*)d_ws;
  // layout: [hbuf u32 x2 524288][flags 1024][hfin 262144][IG 201326592]
  unsigned* hbuf     = (unsigned*)ws;
  unsigned* flags    = (unsigned*)(ws + 524288);
  float* hfin        = (float*)(ws + 525312);
  unsigned short* IG = (unsigned short*)(ws + 787456);
  const size_t need_min = 787456;
  const size_t need_ig  = 787456 + (size_t)NB * NT * NG * 2;  // ~203 MB
  if (ws_size < need_min) return;

  // zero tagged h buffers + flags (tag/flag 0 < any live value)
  hipMemsetAsync(ws, 0, 525312, stream);

  const bool useIG = (ws_size >= need_ig);
  if (useIG) {
    ig_gemm<<<dim3(512, 12), 256, 0, stream>>>(x, Wih, bias, IG);
    gru_rec<true><<<64, 256, 0, stream>>>(x, Wih, Whh, bias, bn, IG, hbuf, flags, hfin);
  } else {
    gru_rec<false><<<64, 256, 0, stream>>>(x, Wih, Whh, bias, bn, nullptr, hbuf, flags, hfin);
  }
  final_linear<<<dim3(32, 8), 256, 0, stream>>>(hfin, Wlin, blin, out);
}